// Round 2
// baseline (1534.072 us; speedup 1.0000x reference)
//
#include <hip/hip_runtime.h>
#include <hip/hip_bf16.h>

#define NE 16
#define NN 4
#define DDIM 128
#define KD 64
#define FD 32
#define HD 45
#define E_SAME 112
#define E_ANTI 128
#define E_NE 64
#define E_TOT 304

// ws float offsets (all multiples of 4 for float4 alignment)
#define OFF_W1T 0        // [3][3][45][32] transposed  (12960)
#define OFF_B1  12960    // [3][3][45]                 (405, pad to 416)
#define OFF_W2  13376    // [3][3][45][64]             (25920)
#define OFF_H0  39296    // [2][64]                    (128)
#define OFF_HWT 39424    // [2][2][64][128] transposed (32768, region reserves more - unused tail)
#define OFF_GW  104960   // [3][3][64][128]            (73728)
#define OFF_YW  178688   // [4][64]                    (256)
#define OFF_XT  178944   // [128]                      (128)
#define OFF_FLAG 179072  // int flag: 1 => inputs are fp32, 0 => bf16

__device__ __forceinline__ float ldf(const void* p, int i, int f32) {
    if (f32) return ((const float*)p)[i];
    unsigned int u = ((unsigned int)((const unsigned short*)p)[i]) << 16;
    return __uint_as_float(u);
}

__global__ void detect_kernel(const unsigned short* rs16, float* ws) {
    __shared__ int bad;
    if (threadIdx.x == 0) bad = 0;
    __syncthreads();
    for (int i = threadIdx.x; i < 2048; i += 256) {
        unsigned int u = ((unsigned int)rs16[i]) << 16;
        float v = __uint_as_float(u);
        if (!(fabsf(v) < 1e6f)) atomicOr(&bad, 1);  // NaN also fails the < test
    }
    __syncthreads();
    if (threadIdx.x == 0) ((int*)(ws + OFF_FLAG))[0] = bad ? 1 : 0;
}

__global__ void prep_kernel(const void* w1, const void* b1,
                            const void* w2, const void* h0,
                            const void* hW, const void* gW,
                            const void* Yw, const void* Xt,
                            float* ws) {
    const int f32 = ((const int*)(ws + OFF_FLAG))[0];
    int i = blockIdx.x * 256 + threadIdx.x;
    if (i < 12960) {  // w1 transpose: [lj][f][h] -> [lj][h][f]
        int lj = i / 1440, rem = i % 1440, h = rem >> 5, f = rem & 31;
        ws[OFF_W1T + i] = ldf(w1, (lj * 32 + f) * 45 + h, f32);
    }
    if (i < 405)   ws[OFF_B1 + i] = ldf(b1, i, f32);
    if (i < 25920) ws[OFF_W2 + i] = ldf(w2, i, f32);
    if (i < 128)   ws[OFF_H0 + i] = ldf(h0, i, f32);
    if (i < 32768) {  // hW transpose: [lj][d][k] -> [lj][k][d]  (2*2*128*64 = 32768)
        int lj = i >> 13, rem = i & 8191, k = rem >> 7, d = rem & 127;
        ws[OFF_HWT + i] = ldf(hW, lj * 8192 + d * 64 + k, f32);
    }
    if (i < 73728) ws[OFF_GW + i] = ldf(gW, i, f32);
    if (i < 256)   ws[OFF_YW + i] = ldf(Yw, i, f32);
    if (i < 128)   ws[OFF_XT + i] = ldf(Xt, i, f32);
}

__global__ __launch_bounds__(256, 2)
void schnet_kernel(const void* __restrict__ rs,
                   const void* __restrict__ coords,
                   const int* __restrict__ same_s, const int* __restrict__ same_r,
                   const int* __restrict__ anti_s, const int* __restrict__ anti_r,
                   const int* __restrict__ ne_s,   const int* __restrict__ ne_r,
                   const float* __restrict__ ws,
                   void* __restrict__ out) {
    const int b = blockIdx.x;
    const int tid = threadIdx.x;
    const int f32 = ((const int*)(ws + OFF_FLAG))[0];

    __shared__ float elec[NE * DDIM];      // 8 KB
    __shared__ float hx[2 * NE * KD];      // 8 KB
    __shared__ float zbuf[NE * KD];        // 4 KB
    __shared__ float nucS[NN * KD];        // 1 KB
    __shared__ float dL[E_TOT], envL[E_TOT];
    __shared__ short esL[E_TOT], erL[E_TOT];
    __shared__ __align__(16) char regionB[38208];
    float* feats_c = (float*)regionB;            // [64][36] = 9216 B
    float* hidT    = (float*)(regionB + 9216);   // [45][64] = 11520 B
    float* w1sT    = (float*)(regionB + 20736);  // [45][32] = 5760 B
    float* b1s     = (float*)(regionB + 26496);  // 48 floats
    float* w2s     = (float*)(regionB + 26688);  // [45][64] = 11520 B
    float* gWs     = (float*)regionB;            // [64][128] = 32768 B (reuses region)

    // ---- init: elec, nuc, distances ----
    for (int i = tid; i < NE * DDIM; i += 256) elec[i] = ws[OFF_XT + (i & 127)];
    for (int i = tid; i < NN * KD; i += 256)   nucS[i] = ws[OFF_YW + i];
    for (int e = tid; e < E_TOT; e += 256) {
        int s, r;
        if (e < E_SAME)            { s = same_s[e];        r = same_r[e]; }
        else if (e < E_SAME+E_ANTI){ s = anti_s[e-E_SAME]; r = anti_r[e-E_SAME]; }
        else                       { s = ne_s[e-240];      r = ne_r[e-240]; }
        long rbase = ((long)b * NE + r) * 3;
        float bx = ldf(rs, rbase + 0, f32);
        float by = ldf(rs, rbase + 1, f32);
        float bz = ldf(rs, rbase + 2, f32);
        float ax, ay, az;
        if (e < 240) {
            long sbase = ((long)b * NE + s) * 3;
            ax = ldf(rs, sbase + 0, f32); ay = ldf(rs, sbase + 1, f32); az = ldf(rs, sbase + 2, f32);
        } else {
            ax = ldf(coords, s*3+0, f32); ay = ldf(coords, s*3+1, f32); az = ldf(coords, s*3+2, f32);
        }
        float dx = ax - bx, dy = ay - by, dz = az - bz;
        float d = sqrtf(dx*dx + dy*dy + dz*dz);
        dL[e] = d;
        envL[e] = d * d * expf(-d);
        esL[e] = (short)s; erL[e] = (short)r;
    }
    __syncthreads();

    for (int l = 0; l < 3; ++l) {
        // ---- hx for j=0,1 (from elec at layer entry) ----
        if (l == 0) {
            for (int i = tid; i < 2 * NE * KD; i += 256) {
                int j = i >> 10, k = i & 63;
                hx[i] = ws[OFF_H0 + j * 64 + k];
            }
        } else {
            const float4* elec4 = (const float4*)elec;
            for (int i = tid; i < 2 * NE * KD; i += 256) {
                int j = i >> 10, rem = i & 1023, s = rem >> 6, k = rem & 63;
                const float4* hrow = (const float4*)(ws + OFF_HWT + ((l-1)*2 + j) * 8192 + k * 128);
                float acc = 0.f;
                #pragma unroll 8
                for (int d4 = 0; d4 < 32; ++d4) {
                    float4 ev = elec4[s * 32 + d4];
                    float4 wv = hrow[d4];
                    acc += ev.x*wv.x + ev.y*wv.y + ev.z*wv.z + ev.w*wv.w;
                }
                hx[i] = acc;
            }
        }
        __syncthreads();

        for (int j = 0; j < 3; ++j) {
            const int lj = l * 3 + j;
            // zero z; stage w1T, b1, w2
            for (int i = tid; i < NE * KD; i += 256) zbuf[i] = 0.f;
            {
                const float4* s1 = (const float4*)(ws + OFF_W1T + lj * 1440);
                float4* d1 = (float4*)w1sT;
                for (int i = tid; i < 360; i += 256) d1[i] = s1[i];
                const float4* s2 = (const float4*)(ws + OFF_W2 + lj * 2880);
                float4* d2 = (float4*)w2s;
                for (int i = tid; i < 720; i += 256) d2[i] = s2[i];
                if (tid < HD) b1s[tid] = ws[OFF_B1 + lj * 45 + tid];
            }
            __syncthreads();

            const int ebase  = (j == 0) ? 0 : ((j == 1) ? E_SAME : 240);
            const int ecount = (j == 0) ? E_SAME : ((j == 1) ? E_ANTI : E_NE);
            for (int c0 = 0; c0 < ecount; c0 += 64) {
                const int nc = min(64, ecount - c0);
                // featurize chunk
                for (int i = tid; i < 64 * FD; i += 256) {
                    int ec = i >> 5, f = i & 31;
                    float v = 0.f;
                    if (ec < nc) {
                        float d   = dL[ebase + c0 + ec];
                        float env = envL[ebase + c0 + ec];
                        float q  = (float)f * (1.0f / 31.0f);
                        float mu = 10.f * q * q;
                        float sg = (1.f + 10.f * q) * (1.f / 7.f);
                        float t  = (d - mu) / sg;
                        v = env * expf(-t * t);
                    }
                    feats_c[ec * 36 + f] = v;
                }
                __syncthreads();
                // MLP layer 1 -> silu -> hidT [h][ec]
                for (int i = tid; i < HD * 64; i += 256) {
                    int h = i >> 6, ec = i & 63;
                    const float4* fr = (const float4*)(feats_c + ec * 36);
                    const float4* wr = (const float4*)(w1sT + h * 32);
                    float acc = b1s[h];
                    #pragma unroll
                    for (int f4 = 0; f4 < 8; ++f4) {
                        float4 fv = fr[f4], wv = wr[f4];
                        acc += fv.x*wv.x + fv.y*wv.y + fv.z*wv.z + fv.w*wv.w;
                    }
                    float sg = 1.f / (1.f + expf(-acc));
                    hidT[h * 64 + ec] = acc * sg;
                }
                __syncthreads();
                // MLP layer 2 (4x4 register tile) + hx mult + scatter to z
                {
                    const int ec0 = (tid >> 4) << 2;
                    const int k0  = (tid & 15) << 2;
                    const int eci = ec0 >> 2, kki = k0 >> 2;
                    float4 a0 = {0,0,0,0}, a1 = a0, a2 = a0, a3 = a0;
                    const float4* hp = (const float4*)hidT;
                    const float4* wp = (const float4*)w2s;
                    for (int h = 0; h < HD; ++h) {
                        float4 hv = hp[h * 16 + eci];
                        float4 wv = wp[h * 16 + kki];
                        a0.x += hv.x*wv.x; a0.y += hv.x*wv.y; a0.z += hv.x*wv.z; a0.w += hv.x*wv.w;
                        a1.x += hv.y*wv.x; a1.y += hv.y*wv.y; a1.z += hv.y*wv.z; a1.w += hv.y*wv.w;
                        a2.x += hv.z*wv.x; a2.y += hv.z*wv.y; a2.z += hv.z*wv.z; a2.w += hv.z*wv.w;
                        a3.x += hv.w*wv.x; a3.y += hv.w*wv.y; a3.z += hv.w*wv.z; a3.w += hv.w*wv.w;
                    }
                    const float* hxbase = (j < 2) ? (hx + (j << 10)) : nucS;
                    float4 av[4] = {a0, a1, a2, a3};
                    #pragma unroll
                    for (int e = 0; e < 4; ++e) {
                        int ec = ec0 + e;
                        if (ec < nc) {
                            int s = esL[ebase + c0 + ec], r = erL[ebase + c0 + ec];
                            const float* hr = hxbase + s * 64 + k0;
                            float* zr = zbuf + r * 64 + k0;
                            atomicAdd(zr + 0, av[e].x * hr[0]);
                            atomicAdd(zr + 1, av[e].y * hr[1]);
                            atomicAdd(zr + 2, av[e].z * hr[2]);
                            atomicAdd(zr + 3, av[e].w * hr[3]);
                        }
                    }
                }
                __syncthreads();
            }
            // stage gW (reuses regionB) then elec += z @ gW
            {
                const float4* src = (const float4*)(ws + OFF_GW + lj * 8192);
                float4* dst = (float4*)gWs;
                for (int i = tid; i < 2048; i += 256) dst[i] = src[i];
            }
            __syncthreads();
            {
                const int r = tid >> 4;
                const int dd0 = (tid & 15) << 3;
                float acc[8] = {0,0,0,0,0,0,0,0};
                const float* zr = zbuf + r * 64;
                #pragma unroll 4
                for (int k = 0; k < KD; ++k) {
                    float zv = zr[k];
                    const float4* g = (const float4*)(gWs + k * 128 + dd0);
                    float4 g0 = g[0], g1 = g[1];
                    acc[0] += zv*g0.x; acc[1] += zv*g0.y; acc[2] += zv*g0.z; acc[3] += zv*g0.w;
                    acc[4] += zv*g1.x; acc[5] += zv*g1.y; acc[6] += zv*g1.z; acc[7] += zv*g1.w;
                }
                float* er2 = elec + r * 128 + dd0;
                #pragma unroll
                for (int q = 0; q < 8; ++q) er2[q] += acc[q];
            }
            __syncthreads();
        }
    }

    if (f32) {
        float* o = (float*)out;
        for (int i = tid; i < NE * DDIM; i += 256)
            o[(long)b * (NE * DDIM) + i] = elec[i];
    } else {
        __hip_bfloat16* o = (__hip_bfloat16*)out;
        for (int i = tid; i < NE * DDIM; i += 256)
            o[(long)b * (NE * DDIM) + i] = __float2bfloat16(elec[i]);
    }
}

extern "C" void kernel_launch(void* const* d_in, const int* in_sizes, int n_in,
                              void* d_out, int out_size, void* d_ws, size_t ws_size,
                              hipStream_t stream) {
    const void* rs     = d_in[0];
    const void* coords = d_in[1];
    const void* X_tab  = d_in[2];
    const void* Y_w    = d_in[3];
    const void* wW1    = d_in[4];
    const void* wb1    = d_in[5];
    const void* wW2    = d_in[6];
    const void* h0     = d_in[7];
    const void* hW     = d_in[8];
    const void* gW     = d_in[9];
    const int* same_s = (const int*)d_in[10];
    const int* same_r = (const int*)d_in[11];
    const int* anti_s = (const int*)d_in[12];
    const int* anti_r = (const int*)d_in[13];
    const int* ne_s   = (const int*)d_in[14];
    const int* ne_r   = (const int*)d_in[15];
    float* ws = (float*)d_ws;

    const int Bn = in_sizes[0] / (NE * 3);

    detect_kernel<<<1, 256, 0, stream>>>((const unsigned short*)rs, ws);
    prep_kernel<<<288, 256, 0, stream>>>(wW1, wb1, wW2, h0, hW, gW, Y_w, X_tab, ws);
    schnet_kernel<<<Bn, 256, 0, stream>>>(rs, coords, same_s, same_r, anti_s, anti_r,
                                          ne_s, ne_r, ws, d_out);
}

// Round 3
// 761.615 us; speedup vs baseline: 2.0142x; 2.0142x over previous
//
#include <hip/hip_runtime.h>
#include <hip/hip_bf16.h>

#define NE 16
#define NN 4
#define DDIM 128
#define KD 64
#define FD 32
#define HD 45
#define E_TOT 304

typedef _Float16 half8 __attribute__((ext_vector_type(8)));
typedef float floatx4 __attribute__((ext_vector_type(4)));

// ws byte offsets
#define OFF_FLAG_B 0
#define OFF_B1_B   64       // fp32 [9][48] (pad cols 45..47 = 0) -> 1728 B
#define OFF_XT_B   1792     // fp32 [128]
#define OFF_H0_B   2304     // f16 [2][64]
#define OFF_YW_B   2560     // f16 [4][64]
#define OFF_W1_B   3072     // f16 frag [9][3nt][512]        = 13824 elems
#define OFF_W2_B   30720    // f16 frag [9][4nt][2kt][512]   = 36864 elems (rows 45..63 zero)
#define OFF_GW_B   104448   // f16 frag [9][8nt][2kt][512]   = 73728 elems
#define OFF_HW_B   251904   // f16 frag [4][4nt][4kt][512]   = 32768 elems

__device__ __forceinline__ float ldf(const void* p, int i, int f32) {
    if (f32) return ((const float*)p)[i];
    unsigned int u = ((unsigned int)((const unsigned short*)p)[i]) << 16;
    return __uint_as_float(u);
}

__global__ void detect_kernel(const unsigned short* rs16, char* wsB) {
    __shared__ int bad;
    if (threadIdx.x == 0) bad = 0;
    __syncthreads();
    for (int i = threadIdx.x; i < 2048; i += 256) {
        unsigned int u = ((unsigned int)rs16[i]) << 16;
        float v = __uint_as_float(u);
        if (!(fabsf(v) < 1e6f)) atomicOr(&bad, 1);
    }
    __syncthreads();
    if (threadIdx.x == 0) *(int*)(wsB + OFF_FLAG_B) = bad ? 1 : 0;
}

__global__ void prep_kernel(const void* w1, const void* b1, const void* w2, const void* h0,
                            const void* hW, const void* gW, const void* Yw, const void* Xt,
                            char* wsB) {
    const int f32 = *(const int*)(wsB + OFF_FLAG_B);
    int i = blockIdx.x * 256 + threadIdx.x;
    _Float16* W1F = (_Float16*)(wsB + OFF_W1_B);
    _Float16* W2F = (_Float16*)(wsB + OFF_W2_B);
    _Float16* GWF = (_Float16*)(wsB + OFF_GW_B);
    _Float16* HWF = (_Float16*)(wsB + OFF_HW_B);
    float*    B1  = (float*)(wsB + OFF_B1_B);
    float*    XT  = (float*)(wsB + OFF_XT_B);
    _Float16* H0F = (_Float16*)(wsB + OFF_H0_B);
    _Float16* YWF = (_Float16*)(wsB + OFF_YW_B);

    if (i < 13824) {  // W1 frags: K=32 (1 kt), N=48 (3 nt), cols>=45 zero
        int lj = i / 1536, rem = i % 1536;
        int nt = rem >> 9, lane = (rem & 511) >> 3, e = rem & 7;
        int row = ((lane >> 4) << 3) + e;
        int col = (nt << 4) + (lane & 15);
        W1F[i] = (_Float16)((col < 45) ? ldf(w1, lj * 1440 + row * 45 + col, f32) : 0.f);
    }
    if (i < 36864) {  // W2 frags: K=64 (2 kt, rows>=45 zero), N=64 (4 nt)
        int lj = i / 4096, rem = i & 4095;
        int nt = rem >> 10, kt = (rem >> 9) & 1, lane = (rem & 511) >> 3, e = rem & 7;
        int row = (kt << 5) + ((lane >> 4) << 3) + e;
        int col = (nt << 4) + (lane & 15);
        W2F[i] = (_Float16)((row < 45) ? ldf(w2, lj * 2880 + row * 64 + col, f32) : 0.f);
    }
    if (i < 73728) {  // gW frags: K=64 (2 kt), N=128 (8 nt)
        int lj = i >> 13, rem = i & 8191;
        int nt = rem >> 10, kt = (rem >> 9) & 1, lane = (rem & 511) >> 3, e = rem & 7;
        int row = (kt << 5) + ((lane >> 4) << 3) + e;
        int col = (nt << 4) + (lane & 15);
        GWF[i] = (_Float16)ldf(gW, lj * 8192 + row * 128 + col, f32);
    }
    if (i < 32768) {  // hW frags: K=128 (4 kt), N=64 (4 nt)
        int lj = i >> 13, rem = i & 8191;
        int nt = rem >> 11, kt = (rem >> 9) & 3, lane = (rem & 511) >> 3, e = rem & 7;
        int row = (kt << 5) + ((lane >> 4) << 3) + e;
        int col = (nt << 4) + (lane & 15);
        HWF[i] = (_Float16)ldf(hW, lj * 8192 + row * 64 + col, f32);
    }
    if (i < 432) { int lj = i / 48, n = i % 48; B1[i] = (n < 45) ? ldf(b1, lj * 45 + n, f32) : 0.f; }
    if (i < 128) XT[i] = ldf(Xt, i, f32);
    if (i < 128) H0F[i] = (_Float16)ldf(h0, i, f32);
    if (i < 256) YWF[i] = (_Float16)ldf(Yw, i, f32);
}

__global__ __launch_bounds__(256)
void schnet_kernel(const void* __restrict__ rs,
                   const void* __restrict__ coords,
                   const int* __restrict__ same_s, const int* __restrict__ same_r,
                   const int* __restrict__ anti_s, const int* __restrict__ anti_r,
                   const int* __restrict__ ne_s,   const int* __restrict__ ne_r,
                   const char* __restrict__ wsB,
                   void* __restrict__ out) {
    const int b   = blockIdx.x;
    const int tid = threadIdx.x;
    const int lane = tid & 63, wv = tid >> 6;
    const int qd = lane >> 4, lm = lane & 15;
    const int f32 = *(const int*)(wsB + OFF_FLAG_B);

    __shared__ __align__(16) float elec[NE * DDIM];        // 8192 B
    __shared__ __align__(16) float zbuf[NE * 68];          // 4352 B (pad stride 68)
    __shared__ __align__(16) _Float16 hxB[3 * NE * KD];    // 6144 B  [j(0,1)|nuc][s][k]
    __shared__ float dL[E_TOT];
    __shared__ unsigned char esL[E_TOT], erL[E_TOT];
    __shared__ __align__(16) _Float16 hid[128 * 72];       // 18432 B (pad stride 72)
    _Float16* elecB = hid;                                  // alias: [16][136] f16, layer-start only

    const float*     B1  = (const float*)(wsB + OFF_B1_B);
    const float*     XT  = (const float*)(wsB + OFF_XT_B);
    const _Float16*  H0F = (const _Float16*)(wsB + OFF_H0_B);
    const _Float16*  YWF = (const _Float16*)(wsB + OFF_YW_B);

    // ---- init ----
    for (int i = tid; i < NE * DDIM; i += 256) elec[i] = XT[i & 127];
    for (int i = tid; i < NN * KD; i += 256)   hxB[2048 + i] = YWF[i];
    for (int i = tid; i < 128 * 72; i += 256)  hid[i] = (_Float16)0.f;
    for (int i = tid; i < NE * 68; i += 256)   zbuf[i] = 0.f;
    for (int e = tid; e < E_TOT; e += 256) {
        int s, r;
        if (e < 112)      { s = same_s[e];       r = same_r[e]; }
        else if (e < 240) { s = anti_s[e - 112]; r = anti_r[e - 112]; }
        else              { s = ne_s[e - 240];   r = ne_r[e - 240]; }
        long rb = ((long)b * NE + r) * 3;
        float bx = ldf(rs, rb + 0, f32), by = ldf(rs, rb + 1, f32), bz = ldf(rs, rb + 2, f32);
        float ax, ay, az;
        if (e < 240) {
            long sb = ((long)b * NE + s) * 3;
            ax = ldf(rs, sb + 0, f32); ay = ldf(rs, sb + 1, f32); az = ldf(rs, sb + 2, f32);
        } else {
            ax = ldf(coords, s * 3 + 0, f32); ay = ldf(coords, s * 3 + 1, f32); az = ldf(coords, s * 3 + 2, f32);
        }
        float dx = ax - bx, dy = ay - by, dz = az - bz;
        dL[e] = sqrtf(dx * dx + dy * dy + dz * dz);
        esL[e] = (unsigned char)s; erL[e] = (unsigned char)r;
    }
    __syncthreads();

    for (int l = 0; l < 3; ++l) {
        // ---- phase H: hxB[0..1] ----
        if (l == 0) {
            for (int i = tid; i < 2048; i += 256) hxB[i] = H0F[((i >> 10) << 6) + (i & 63)];
            __syncthreads();
        } else {
            for (int i = tid; i < 2048; i += 256) {
                int s = i >> 7, d = i & 127;
                elecB[s * 136 + d] = (_Float16)elec[s * 128 + d];
            }
            __syncthreads();
            for (int t = wv; t < 8; t += 4) {
                int j = t >> 2, nt = t & 3;
                const half8* Bb = (const half8*)(wsB + OFF_HW_B) + (((l - 1) * 2 + j) * 8192 + nt * 2048) / 8;
                floatx4 acc = {0.f, 0.f, 0.f, 0.f};
                #pragma unroll
                for (int kt = 0; kt < 4; ++kt) {
                    half8 a = *(const half8*)(&elecB[lm * 136 + kt * 32 + qd * 8]);
                    half8 bf = Bb[kt * 64 + lane];
                    acc = __builtin_amdgcn_mfma_f32_16x16x32_f16(a, bf, acc, 0, 0, 0);
                }
                #pragma unroll
                for (int r = 0; r < 4; ++r)
                    hxB[j * 1024 + (qd * 4 + r) * 64 + nt * 16 + lm] = (_Float16)acc[r];
            }
            __syncthreads();
        }

        for (int j = 0; j < 3; ++j) {
            const int lj = l * 3 + j;
            const int Mtiles = (j == 0) ? 7 : ((j == 1) ? 8 : 4);
            const int ebase  = (j == 0) ? 0 : ((j == 1) ? 112 : 240);

            // ---- MLP1 (featurize-in-regs -> MFMA -> silu -> hid) + zero zbuf ----
            for (int i = tid; i < NE * 68; i += 256) zbuf[i] = 0.f;
            {
                const half8* B1f = (const half8*)(wsB + OFF_W1_B) + (lj * 1536) / 8;
                half8 w0 = B1f[lane], w1v = B1f[64 + lane], w2v = B1f[128 + lane];
                const float* bias = B1 + lj * 48;
                float bi0 = bias[lm], bi1 = bias[16 + lm], bi2 = bias[32 + lm];
                for (int mt = wv; mt < Mtiles; mt += 4) {
                    int m = mt * 16 + lm;
                    float d = dL[ebase + m];
                    float env = d * d * __expf(-d);
                    half8 a;
                    #pragma unroll
                    for (int ii = 0; ii < 8; ++ii) {
                        float qf = (float)(qd * 8 + ii) * (1.f / 31.f);
                        float mu = 10.f * qf * qf;
                        float sg = (1.f + 10.f * qf) * (1.f / 7.f);
                        float tt = (d - mu) / sg;
                        a[ii] = (_Float16)(env * __expf(-tt * tt));
                    }
                    floatx4 c0 = {0.f,0.f,0.f,0.f}, c1 = c0, c2 = c0;
                    c0 = __builtin_amdgcn_mfma_f32_16x16x32_f16(a, w0,  c0, 0, 0, 0);
                    c1 = __builtin_amdgcn_mfma_f32_16x16x32_f16(a, w1v, c1, 0, 0, 0);
                    c2 = __builtin_amdgcn_mfma_f32_16x16x32_f16(a, w2v, c2, 0, 0, 0);
                    #pragma unroll
                    for (int r = 0; r < 4; ++r) {
                        int row = mt * 16 + qd * 4 + r;
                        float v0 = c0[r] + bi0, v1 = c1[r] + bi1, v2 = c2[r] + bi2;
                        v0 = v0 / (1.f + __expf(-v0));
                        v1 = v1 / (1.f + __expf(-v1));
                        v2 = v2 / (1.f + __expf(-v2));
                        hid[row * 72 + lm]      = (_Float16)v0;
                        hid[row * 72 + 16 + lm] = (_Float16)v1;
                        hid[row * 72 + 32 + lm] = (_Float16)v2;
                    }
                }
            }
            __syncthreads();

            // ---- MLP2 -> we -> *hx gather -> atomic scatter into zbuf ----
            {
                const int nt = wv;  // 4 waves = 4 n-tiles
                const half8* B2f = (const half8*)(wsB + OFF_W2_B) + (lj * 4096 + nt * 1024) / 8;
                half8 bk0 = B2f[lane], bk1 = B2f[64 + lane];
                const _Float16* hxsel = hxB + ((j < 2) ? j : 2) * 1024;
                const int k = nt * 16 + lm;
                for (int mt = 0; mt < Mtiles; ++mt) {
                    half8 a0 = *(const half8*)(&hid[(mt * 16 + lm) * 72 + qd * 8]);
                    half8 a1 = *(const half8*)(&hid[(mt * 16 + lm) * 72 + 32 + qd * 8]);
                    floatx4 acc = {0.f,0.f,0.f,0.f};
                    acc = __builtin_amdgcn_mfma_f32_16x16x32_f16(a0, bk0, acc, 0, 0, 0);
                    acc = __builtin_amdgcn_mfma_f32_16x16x32_f16(a1, bk1, acc, 0, 0, 0);
                    #pragma unroll
                    for (int r = 0; r < 4; ++r) {
                        int e = ebase + mt * 16 + qd * 4 + r;
                        int s = esL[e], rr = erL[e];
                        float weh = acc[r] * (float)hxsel[s * 64 + k];
                        atomicAdd(&zbuf[rr * 68 + k], weh);
                    }
                }
            }
            __syncthreads();

            // ---- elec += z @ gW (MFMA, C seeded from elec) ----
            {
                floatx4 za0a = *(const floatx4*)(&zbuf[lm * 68 + qd * 8]);
                floatx4 za0b = *(const floatx4*)(&zbuf[lm * 68 + qd * 8 + 4]);
                floatx4 za1a = *(const floatx4*)(&zbuf[lm * 68 + 32 + qd * 8]);
                floatx4 za1b = *(const floatx4*)(&zbuf[lm * 68 + 32 + qd * 8 + 4]);
                half8 A0, A1;
                #pragma unroll
                for (int ii = 0; ii < 4; ++ii) {
                    A0[ii] = (_Float16)za0a[ii]; A0[4 + ii] = (_Float16)za0b[ii];
                    A1[ii] = (_Float16)za1a[ii]; A1[4 + ii] = (_Float16)za1b[ii];
                }
                for (int t = wv; t < 8; t += 4) {
                    const half8* Gf = (const half8*)(wsB + OFF_GW_B) + (lj * 8192 + t * 1024) / 8;
                    half8 g0 = Gf[lane], g1 = Gf[64 + lane];
                    floatx4 acc;
                    #pragma unroll
                    for (int r = 0; r < 4; ++r) acc[r] = elec[(qd * 4 + r) * 128 + t * 16 + lm];
                    acc = __builtin_amdgcn_mfma_f32_16x16x32_f16(A0, g0, acc, 0, 0, 0);
                    acc = __builtin_amdgcn_mfma_f32_16x16x32_f16(A1, g1, acc, 0, 0, 0);
                    #pragma unroll
                    for (int r = 0; r < 4; ++r) elec[(qd * 4 + r) * 128 + t * 16 + lm] = acc[r];
                }
            }
            __syncthreads();
        }
    }

    if (f32) {
        float* o = (float*)out;
        for (int i = tid; i < NE * DDIM; i += 256) o[(long)b * (NE * DDIM) + i] = elec[i];
    } else {
        __hip_bfloat16* o = (__hip_bfloat16*)out;
        for (int i = tid; i < NE * DDIM; i += 256) o[(long)b * (NE * DDIM) + i] = __float2bfloat16(elec[i]);
    }
}

extern "C" void kernel_launch(void* const* d_in, const int* in_sizes, int n_in,
                              void* d_out, int out_size, void* d_ws, size_t ws_size,
                              hipStream_t stream) {
    const void* rs     = d_in[0];
    const void* coords = d_in[1];
    const void* X_tab  = d_in[2];
    const void* Y_w    = d_in[3];
    const void* wW1    = d_in[4];
    const void* wb1    = d_in[5];
    const void* wW2    = d_in[6];
    const void* h0     = d_in[7];
    const void* hW     = d_in[8];
    const void* gW     = d_in[9];
    const int* same_s = (const int*)d_in[10];
    const int* same_r = (const int*)d_in[11];
    const int* anti_s = (const int*)d_in[12];
    const int* anti_r = (const int*)d_in[13];
    const int* ne_s   = (const int*)d_in[14];
    const int* ne_r   = (const int*)d_in[15];
    char* wsB = (char*)d_ws;

    const int Bn = in_sizes[0] / (NE * 3);

    detect_kernel<<<1, 256, 0, stream>>>((const unsigned short*)rs, wsB);
    prep_kernel<<<288, 256, 0, stream>>>(wW1, wb1, wW2, h0, hW, gW, Y_w, X_tab, wsB);
    schnet_kernel<<<Bn, 256, 0, stream>>>(rs, coords, same_s, same_r, anti_s, anti_r,
                                          ne_s, ne_r, wsB, d_out);
}

// Round 4
// 719.135 us; speedup vs baseline: 2.1332x; 1.0591x over previous
//
#include <hip/hip_runtime.h>
#include <hip/hip_bf16.h>

#define NE 16
#define NN 4
#define DDIM 128
#define KD 64
#define HD 45
#define E_TOT 304

typedef _Float16 half8 __attribute__((ext_vector_type(8)));
typedef float floatx4 __attribute__((ext_vector_type(4)));

// ws byte offsets
#define OFF_FLAG_B 0
#define OFF_B1_B   64       // fp32 [9][48] (pad cols 45..47 = 0)
#define OFF_XT_B   1792     // fp32 [128]
#define OFF_H0_B   2304     // f16 [2][64]
#define OFF_YW_B   2560     // f16 [4][64]
#define OFF_W1_B   3072     // f16 frag [9][3nt][512]
#define OFF_W2_B   30720    // f16 frag [9][4nt][2kt][512] (rows 45..63 zero)
#define OFF_GW_B   104448   // f16 frag [9][8nt][2kt][512]
#define OFF_HW_B   251904   // f16 frag [4][4nt][4kt][512]

__device__ __forceinline__ float ldf(const void* p, long i, int f32) {
    if (f32) return ((const float*)p)[i];
    unsigned int u = ((unsigned int)((const unsigned short*)p)[i]) << 16;
    return __uint_as_float(u);
}

__global__ void detect_kernel(const unsigned short* rs16, char* wsB) {
    __shared__ int bad;
    if (threadIdx.x == 0) bad = 0;
    __syncthreads();
    for (int i = threadIdx.x; i < 2048; i += 256) {
        unsigned int u = ((unsigned int)rs16[i]) << 16;
        float v = __uint_as_float(u);
        if (!(fabsf(v) < 1e6f)) atomicOr(&bad, 1);
    }
    __syncthreads();
    if (threadIdx.x == 0) *(int*)(wsB + OFF_FLAG_B) = bad ? 1 : 0;
}

__global__ void prep_kernel(const void* w1, const void* b1, const void* w2, const void* h0,
                            const void* hW, const void* gW, const void* Yw, const void* Xt,
                            char* wsB) {
    const int f32 = *(const int*)(wsB + OFF_FLAG_B);
    int i = blockIdx.x * 256 + threadIdx.x;
    _Float16* W1F = (_Float16*)(wsB + OFF_W1_B);
    _Float16* W2F = (_Float16*)(wsB + OFF_W2_B);
    _Float16* GWF = (_Float16*)(wsB + OFF_GW_B);
    _Float16* HWF = (_Float16*)(wsB + OFF_HW_B);
    float*    B1  = (float*)(wsB + OFF_B1_B);
    float*    XT  = (float*)(wsB + OFF_XT_B);
    _Float16* H0F = (_Float16*)(wsB + OFF_H0_B);
    _Float16* YWF = (_Float16*)(wsB + OFF_YW_B);

    if (i < 13824) {  // W1 frags
        int lj = i / 1536, rem = i % 1536;
        int nt = rem >> 9, lane = (rem & 511) >> 3, e = rem & 7;
        int row = ((lane >> 4) << 3) + e;
        int col = (nt << 4) + (lane & 15);
        W1F[i] = (_Float16)((col < 45) ? ldf(w1, lj * 1440 + row * 45 + col, f32) : 0.f);
    }
    if (i < 36864) {  // W2 frags (rows >= 45 zero)
        int lj = i / 4096, rem = i & 4095;
        int nt = rem >> 10, kt = (rem >> 9) & 1, lane = (rem & 511) >> 3, e = rem & 7;
        int row = (kt << 5) + ((lane >> 4) << 3) + e;
        int col = (nt << 4) + (lane & 15);
        W2F[i] = (_Float16)((row < 45) ? ldf(w2, lj * 2880 + row * 64 + col, f32) : 0.f);
    }
    if (i < 73728) {  // gW frags
        int lj = i >> 13, rem = i & 8191;
        int nt = rem >> 10, kt = (rem >> 9) & 1, lane = (rem & 511) >> 3, e = rem & 7;
        int row = (kt << 5) + ((lane >> 4) << 3) + e;
        int col = (nt << 4) + (lane & 15);
        GWF[i] = (_Float16)ldf(gW, lj * 8192 + row * 128 + col, f32);
    }
    if (i < 32768) {  // hW frags
        int lj = i >> 13, rem = i & 8191;
        int nt = rem >> 11, kt = (rem >> 9) & 3, lane = (rem & 511) >> 3, e = rem & 7;
        int row = (kt << 5) + ((lane >> 4) << 3) + e;
        int col = (nt << 4) + (lane & 15);
        HWF[i] = (_Float16)ldf(hW, lj * 8192 + row * 64 + col, f32);
    }
    if (i < 432) { int lj = i / 48, n = i % 48; B1[i] = (n < 45) ? ldf(b1, lj * 45 + n, f32) : 0.f; }
    if (i < 128) XT[i] = ldf(Xt, i, f32);
    if (i < 128) H0F[i] = (_Float16)ldf(h0, i, f32);
    if (i < 256) YWF[i] = (_Float16)ldf(Yw, i, f32);
}

__device__ __forceinline__ half8 mkfeat(float d, int qd) {
    float env = d * d * __expf(-d);
    half8 a;
    #pragma unroll
    for (int ii = 0; ii < 8; ++ii) {
        float qf = (float)(qd * 8 + ii) * (1.f / 31.f);
        float mu = 10.f * qf * qf;
        float isg = 7.f * __builtin_amdgcn_rcpf(1.f + 10.f * qf);
        float tt = (d - mu) * isg;
        a[ii] = (_Float16)(env * __expf(-tt * tt));
    }
    return a;
}

template<int MT>
__device__ __forceinline__ void edge_class(
    const half8 (&fa)[MT], int ebase,
    const _Float16* __restrict__ hxsel,           // [s][68]
    const unsigned char* __restrict__ esS, const unsigned char* __restrict__ erS,
    _Float16* __restrict__ hid0, _Float16* __restrict__ hid1,  // [16][72] each
    float* __restrict__ zbuf,                     // [16][68]
    const half8* __restrict__ W1F_lj, const float* __restrict__ B1_lj,
    const half8* __restrict__ W2F_lj,
    int lane, int qd, int lm)
{
    half8 w0 = W1F_lj[lane], w1v = W1F_lj[64 + lane], w2v = W1F_lj[128 + lane];
    float bi0 = B1_lj[lm], bi1 = B1_lj[16 + lm], bi2 = B1_lj[32 + lm];
    half8 bk[4][2];
    #pragma unroll
    for (int nt = 0; nt < 4; ++nt) {
        bk[nt][0] = W2F_lj[nt * 128 + lane];
        bk[nt][1] = W2F_lj[nt * 128 + 64 + lane];
    }
    #pragma unroll
    for (int mt = 0; mt < MT; ++mt) {
        _Float16* hidb = (mt & 1) ? hid1 : hid0;
        floatx4 c0 = {0.f,0.f,0.f,0.f}, c1 = c0, c2 = c0;
        c0 = __builtin_amdgcn_mfma_f32_16x16x32_f16(fa[mt], w0,  c0, 0, 0, 0);
        c1 = __builtin_amdgcn_mfma_f32_16x16x32_f16(fa[mt], w1v, c1, 0, 0, 0);
        c2 = __builtin_amdgcn_mfma_f32_16x16x32_f16(fa[mt], w2v, c2, 0, 0, 0);
        #pragma unroll
        for (int r = 0; r < 4; ++r) {
            int row = qd * 4 + r;
            float v0 = c0[r] + bi0, v1 = c1[r] + bi1, v2 = c2[r] + bi2;
            v0 = v0 * __builtin_amdgcn_rcpf(1.f + __expf(-v0));
            v1 = v1 * __builtin_amdgcn_rcpf(1.f + __expf(-v1));
            v2 = v2 * __builtin_amdgcn_rcpf(1.f + __expf(-v2));
            hidb[row * 72 + lm]      = (_Float16)v0;
            hidb[row * 72 + 16 + lm] = (_Float16)v1;
            hidb[row * 72 + 32 + lm] = (_Float16)v2;
        }
        half8 a0 = *(const half8*)(hidb + lm * 72 + qd * 8);
        half8 a1 = *(const half8*)(hidb + lm * 72 + 32 + qd * 8);
        #pragma unroll
        for (int nt = 0; nt < 4; ++nt) {
            floatx4 acc = {0.f,0.f,0.f,0.f};
            acc = __builtin_amdgcn_mfma_f32_16x16x32_f16(a0, bk[nt][0], acc, 0, 0, 0);
            acc = __builtin_amdgcn_mfma_f32_16x16x32_f16(a1, bk[nt][1], acc, 0, 0, 0);
            #pragma unroll
            for (int r = 0; r < 4; ++r) {
                int e = ebase + mt * 16 + qd * 4 + r;
                int s = esS[e], rr = erS[e];
                float weh = acc[r] * (float)hxsel[s * 68 + nt * 16 + lm];
                atomicAdd(&zbuf[rr * 68 + nt * 16 + lm], weh);
            }
        }
    }
}

__global__ __launch_bounds__(256, 2)
void schnet_kernel(const void* __restrict__ rs,
                   const void* __restrict__ coords,
                   const int* __restrict__ same_s, const int* __restrict__ same_r,
                   const int* __restrict__ anti_s, const int* __restrict__ anti_r,
                   const int* __restrict__ ne_s,   const int* __restrict__ ne_r,
                   const char* __restrict__ wsB,
                   void* __restrict__ out, int Bn) {
    const int tid = threadIdx.x;
    const int wv = tid >> 6, lane = tid & 63;
    const int qd = lane >> 4, lm = lane & 15;
    const int f32 = *(const int*)(wsB + OFF_FLAG_B);

    __shared__ float dLA[4][304];
    __shared__ float zbufA[4][16 * 68];
    __shared__ _Float16 hxA[4][2 * 16 * 68];
    __shared__ _Float16 scrA[4][2304];     // union: elecB [16][136] | hid0/hid1 [16][72]x2
    __shared__ _Float16 nucS[4 * 68];
    __shared__ unsigned char esS[E_TOT], erS[E_TOT];

    const float*    B1  = (const float*)(wsB + OFF_B1_B);
    const float*    XT  = (const float*)(wsB + OFF_XT_B);
    const _Float16* H0F = (const _Float16*)(wsB + OFF_H0_B);
    const _Float16* YWF = (const _Float16*)(wsB + OFF_YW_B);
    const half8*    W1F = (const half8*)(wsB + OFF_W1_B);
    const half8*    W2F = (const half8*)(wsB + OFF_W2_B);
    const half8*    GWF = (const half8*)(wsB + OFF_GW_B);
    const half8*    HWF = (const half8*)(wsB + OFF_HW_B);

    // ---- block-coop init: edge indices + nuc (b-independent) ----
    for (int i = tid; i < E_TOT; i += 256) {
        int s, r;
        if (i < 112)      { s = same_s[i];       r = same_r[i]; }
        else if (i < 240) { s = anti_s[i - 112]; r = anti_r[i - 112]; }
        else              { s = ne_s[i - 240];   r = ne_r[i - 240]; }
        esS[i] = (unsigned char)s; erS[i] = (unsigned char)r;
    }
    for (int i = tid; i < NN * KD; i += 256)
        nucS[(i >> 6) * 68 + (i & 63)] = YWF[i];
    __syncthreads();

    // ---- per-wave: one batch element ----
    int b = blockIdx.x * 4 + wv;
    if (b >= Bn) b = Bn - 1;   // duplicate work; identical values -> benign

    float*     dLw   = dLA[wv];
    float*     zbuf  = zbufA[wv];
    _Float16*  hxB   = hxA[wv];
    _Float16*  elecB = scrA[wv];
    _Float16*  hid0  = scrA[wv];
    _Float16*  hid1  = scrA[wv] + 1152;

    // distances
    for (int e = lane; e < E_TOT; e += 64) {
        int s = esS[e], r = erS[e];
        long rb = ((long)b * NE + r) * 3;
        float bx = ldf(rs, rb + 0, f32), by = ldf(rs, rb + 1, f32), bz = ldf(rs, rb + 2, f32);
        float ax, ay, az;
        if (e < 240) {
            long sb = ((long)b * NE + s) * 3;
            ax = ldf(rs, sb + 0, f32); ay = ldf(rs, sb + 1, f32); az = ldf(rs, sb + 2, f32);
        } else {
            ax = ldf(coords, s * 3 + 0, f32); ay = ldf(coords, s * 3 + 1, f32); az = ldf(coords, s * 3 + 2, f32);
        }
        float dx = ax - bx, dy = ay - by, dz = az - bz;
        dLw[e] = sqrtf(dx * dx + dy * dy + dz * dz);
    }

    // featurize ONCE into registers (A-frags), reused by all 3 layers
    half8 faS[7], faA[8], faN[4];
    #pragma unroll
    for (int mt = 0; mt < 7; ++mt) faS[mt] = mkfeat(dLw[mt * 16 + lm], qd);
    #pragma unroll
    for (int mt = 0; mt < 8; ++mt) faA[mt] = mkfeat(dLw[112 + mt * 16 + lm], qd);
    #pragma unroll
    for (int mt = 0; mt < 4; ++mt) faN[mt] = mkfeat(dLw[240 + mt * 16 + lm], qd);

    // elec state in registers (C-layout): eacc[t][r] = elec[qd*4+r][t*16+lm]
    floatx4 eacc[8];
    #pragma unroll
    for (int t = 0; t < 8; ++t) {
        float xv = XT[t * 16 + lm];
        eacc[t][0] = xv; eacc[t][1] = xv; eacc[t][2] = xv; eacc[t][3] = xv;
    }

    // hx for l=0: h0 broadcast over senders
    for (int i = lane; i < 2 * NE * KD; i += 64) {
        int j = i >> 10, s = (i >> 6) & 15, k = i & 63;
        hxB[j * 1088 + s * 68 + k] = H0F[j * 64 + k];
    }

    for (int l = 0; l < 3; ++l) {
        if (l > 0) {
            // elecB <- eacc (f16, A-layout-readable)
            #pragma unroll
            for (int t = 0; t < 8; ++t)
                #pragma unroll
                for (int r = 0; r < 4; ++r)
                    elecB[(qd * 4 + r) * 136 + t * 16 + lm] = (_Float16)eacc[t][r];
            half8 ae[4];
            #pragma unroll
            for (int kt = 0; kt < 4; ++kt)
                ae[kt] = *(const half8*)(elecB + lm * 136 + kt * 32 + qd * 8);
            #pragma unroll
            for (int j = 0; j < 2; ++j) {
                int lj4 = (l - 1) * 2 + j;
                #pragma unroll
                for (int nt = 0; nt < 4; ++nt) {
                    const half8* Bb = HWF + (lj4 * 4 + nt) * 4 * 64;
                    floatx4 acc = {0.f,0.f,0.f,0.f};
                    #pragma unroll
                    for (int kt = 0; kt < 4; ++kt)
                        acc = __builtin_amdgcn_mfma_f32_16x16x32_f16(ae[kt], Bb[kt * 64 + lane], acc, 0, 0, 0);
                    #pragma unroll
                    for (int r = 0; r < 4; ++r)
                        hxB[j * 1088 + (qd * 4 + r) * 68 + nt * 16 + lm] = (_Float16)acc[r];
                }
            }
        }

        #pragma unroll
        for (int j = 0; j < 3; ++j) {
            const int lj = l * 3 + j;
            for (int i = lane; i < 16 * 68; i += 64) zbuf[i] = 0.f;

            const half8* W1F_lj = W1F + lj * 192;
            const float* B1_lj  = B1 + lj * 48;
            const half8* W2F_lj = W2F + lj * 512;
            if (j == 0)
                edge_class<7>(faS, 0,   hxB,        esS, erS, hid0, hid1, zbuf, W1F_lj, B1_lj, W2F_lj, lane, qd, lm);
            else if (j == 1)
                edge_class<8>(faA, 112, hxB + 1088, esS, erS, hid0, hid1, zbuf, W1F_lj, B1_lj, W2F_lj, lane, qd, lm);
            else
                edge_class<4>(faN, 240, nucS,       esS, erS, hid0, hid1, zbuf, W1F_lj, B1_lj, W2F_lj, lane, qd, lm);

            // elec += z @ gW
            floatx4 za0a = *(const floatx4*)(zbuf + lm * 68 + qd * 8);
            floatx4 za0b = *(const floatx4*)(zbuf + lm * 68 + qd * 8 + 4);
            floatx4 za1a = *(const floatx4*)(zbuf + lm * 68 + 32 + qd * 8);
            floatx4 za1b = *(const floatx4*)(zbuf + lm * 68 + 32 + qd * 8 + 4);
            half8 A0, A1;
            #pragma unroll
            for (int ii = 0; ii < 4; ++ii) {
                A0[ii] = (_Float16)za0a[ii]; A0[4 + ii] = (_Float16)za0b[ii];
                A1[ii] = (_Float16)za1a[ii]; A1[4 + ii] = (_Float16)za1b[ii];
            }
            const half8* GWF_lj = GWF + lj * 1024;
            #pragma unroll
            for (int t = 0; t < 8; ++t) {
                half8 g0 = GWF_lj[t * 128 + lane];
                half8 g1 = GWF_lj[t * 128 + 64 + lane];
                eacc[t] = __builtin_amdgcn_mfma_f32_16x16x32_f16(A0, g0, eacc[t], 0, 0, 0);
                eacc[t] = __builtin_amdgcn_mfma_f32_16x16x32_f16(A1, g1, eacc[t], 0, 0, 0);
            }
        }
    }

    // store
    if (f32) {
        float* o = (float*)out + (long)b * (NE * DDIM);
        #pragma unroll
        for (int t = 0; t < 8; ++t)
            #pragma unroll
            for (int r = 0; r < 4; ++r)
                o[(qd * 4 + r) * 128 + t * 16 + lm] = eacc[t][r];
    } else {
        __hip_bfloat16* o = (__hip_bfloat16*)out + (long)b * (NE * DDIM);
        #pragma unroll
        for (int t = 0; t < 8; ++t)
            #pragma unroll
            for (int r = 0; r < 4; ++r)
                o[(qd * 4 + r) * 128 + t * 16 + lm] = __float2bfloat16(eacc[t][r]);
    }
}

extern "C" void kernel_launch(void* const* d_in, const int* in_sizes, int n_in,
                              void* d_out, int out_size, void* d_ws, size_t ws_size,
                              hipStream_t stream) {
    const void* rs     = d_in[0];
    const void* coords = d_in[1];
    const void* X_tab  = d_in[2];
    const void* Y_w    = d_in[3];
    const void* wW1    = d_in[4];
    const void* wb1    = d_in[5];
    const void* wW2    = d_in[6];
    const void* h0     = d_in[7];
    const void* hW     = d_in[8];
    const void* gW     = d_in[9];
    const int* same_s = (const int*)d_in[10];
    const int* same_r = (const int*)d_in[11];
    const int* anti_s = (const int*)d_in[12];
    const int* anti_r = (const int*)d_in[13];
    const int* ne_s   = (const int*)d_in[14];
    const int* ne_r   = (const int*)d_in[15];
    char* wsB = (char*)d_ws;

    const int Bn = in_sizes[0] / (NE * 3);

    detect_kernel<<<1, 256, 0, stream>>>((const unsigned short*)rs, wsB);
    prep_kernel<<<288, 256, 0, stream>>>(wW1, wb1, wW2, h0, hW, gW, Y_w, X_tab, wsB);
    schnet_kernel<<<(Bn + 3) / 4, 256, 0, stream>>>(rs, coords, same_s, same_r, anti_s, anti_r,
                                                    ne_s, ne_r, wsB, d_out, Bn);
}